// Round 11
// baseline (3259.934 us; speedup 1.0000x reference)
//
#include <hip/hip_runtime.h>

#define NB   256
#define ND   512
#define NH4  2048
#define NL   3
#define NT   201
#define NV   128
#define NMID 1024

typedef _Float16 half8 __attribute__((ext_vector_type(8)));
typedef float f32x4 __attribute__((ext_vector_type(4)));

__device__ __forceinline__ float sigf(float x) { return 1.0f / (1.0f + __expf(-x)); }
__device__ __forceinline__ float tanh_(float x) {
  float e = __expf(-2.0f * fabsf(x));
  float t = (1.0f - e) / (1.0f + e);
  return x < 0.0f ? -t : t;
}

// 16B load issued to L2 (sc0); freshness ensured by the single buffer_inv at
// barrier exit (sc0 alone does NOT bypass L1 - r3 lesson).
__device__ __forceinline__ half8 l2_load(const _Float16* p) {
  half8 v;
  asm volatile("global_load_dwordx4 %0, %1, off sc0" : "=v"(v) : "v"(p));
  return v;
}

// Genuine atomic RMW at the issuing XCD's L2 (r5-proven). ~300cy round trip.
__device__ __forceinline__ unsigned l2_rmw_add(unsigned* p, unsigned val) {
  unsigned v;
  asm volatile("global_atomic_add %0, %1, %2, off sc0\n\ts_waitcnt vmcnt(0)"
               : "=v"(v) : "v"(p), "v"(val) : "memory");
  return v;
}

// XCD-local barrier core (r5-proven): all-RMW arrive+poll on one L2 line.
// buffer_inv exactly ONCE at exit (r6 lesson). r11: phase-aware backoff --
// arrival index tells how many WGs are still out; early arrivers sleep 512cy
// before first poll (fewer contending RMWs, late arrivals unaffected).
// Release drain (vmcnt) is done by the CALLER with literal counts so that
// res-stores / prefetch-loads can remain in flight across the barrier.
__device__ __forceinline__ void xbar_core(unsigned* cnt) {
  __syncthreads();
  if (threadIdx.x == 0) {
    unsigned old = l2_rmw_add(cnt, 1u);
    unsigned target = (old & ~31u) + 32u;
    int ahead = 31 - (int)(old & 31u);
    if (ahead > 8) __builtin_amdgcn_s_sleep(8);   // 512cy initial backoff
    int guard = 1 << 16;
    while (l2_rmw_add(cnt, 0u) < target && --guard)
      __builtin_amdgcn_s_sleep(2);
  }
  __syncthreads();
  asm volatile("buffer_inv" ::: "memory");   // L1-only invalidate, once
  __builtin_amdgcn_sched_barrier(0);
}

// ---------------- fused prep kernel ----------------
__global__ void prep_all(const float* __restrict__ Wih, const float* __restrict__ Whh,
                         const float* __restrict__ bih, const float* __restrict__ bhh,
                         const float* __restrict__ Wvis, const float* __restrict__ feat,
                         const float* __restrict__ embed, const float* __restrict__ W1,
                         const float* __restrict__ W2,
                         _Float16* __restrict__ Wp, float* __restrict__ bp,
                         _Float16* __restrict__ Wvis16, _Float16* __restrict__ feat16,
                         _Float16* __restrict__ x0, _Float16* __restrict__ W1h,
                         _Float16* __restrict__ W2h, unsigned* __restrict__ cnt) {
  size_t idx = (size_t)blockIdx.x * 256 + threadIdx.x;   // 3*2048*1024 total
  {
    int k = (int)(idx & 1023);
    int R = (int)((idx >> 10) & 2047);
    int l = (int)(idx >> 21);
    int dt = R >> 6, g = (R >> 4) & 3, di = R & 15;
    int col = g * 512 + dt * 16 + di;
    float v = (k < 512) ? Wih[((size_t)l * NH4 + col) * ND + k]
                        : Whh[((size_t)l * NH4 + col) * ND + (k - 512)];
    Wp[idx] = (_Float16)v;
  }
  if (idx < (size_t)NL * NH4) {
    int R = (int)(idx & 2047);
    int l = (int)(idx >> 11);
    int dt = R >> 6, g = (R >> 4) & 3, di = R & 15;
    int col = g * 512 + dt * 16 + di;
    bp[idx] = bih[l * NH4 + col] + bhh[l * NH4 + col];
  }
  if (idx < 512 * 512)  Wvis16[idx] = (_Float16)Wvis[idx];
  if (idx < 256 * 512)  feat16[idx] = (_Float16)feat[idx];
  if (idx < 256 * 512)  x0[idx]     = (_Float16)embed[idx & 511];   // embed[START_IDX=0]
  if (idx < 1024 * 512) W1h[idx]    = (_Float16)W1[idx];
  if (idx < 128 * 1024) W2h[idx]    = (_Float16)W2[idx];
  if (idx < 1024) cnt[idx] = 0;
}

// ---------------- persistent LSTM kernel ----------------
// r7/r10 structure (proven): 256 WGs x 512 threads, 160KB LDS -> 1 WG/CU ->
// 32 WGs/XCD, 2 waves/SIMD. K split 8 ways: waves 0-3 x-half, 4-7 h-half.
// Layer-0 weights in LDS, layers 1-2 in registers.
// r11: (a) res stores excluded from the release drain (they write-allocate
// cold HBM lines, ~900cy ack - FETCH_SIZE == sizeof(res) was the tell);
// (b) l0 B-frags kk=0,1 prefetched into regs across the l2->l0 barrier;
// (c) phase-aware barrier backoff.
__global__ __launch_bounds__(512, 2) void lstm_persist(
    const _Float16* __restrict__ Wp,     // [3][2048][1024] permuted
    const float* __restrict__ bp,        // [3][2048]
    const _Float16* __restrict__ Wvis,   // [512][512]
    const float* __restrict__ bvis,      // [512]
    const _Float16* __restrict__ feat16, // [256][512]
    const _Float16* __restrict__ x0,     // [256][512]
    _Float16* __restrict__ featp,        // [256][512]
    _Float16* __restrict__ hbuf,         // [3][2][256][512]
    _Float16* __restrict__ res,          // [201][256][512]
    unsigned* __restrict__ cntbase) {
  __shared__ _Float16 wlds[64][1024];          // 128KB layer-0 weights
  __shared__ float expart[4][32][16][4];       // 32KB: [slice][batch][di][gate]
  // total LDS = 163840 B exactly (gfx950 per-WG limit)

  const int tid = threadIdx.x;
  const int lane = tid & 63, w = tid >> 6;     // w = 0..7
  const int lr = lane & 15, lg = (lane >> 4) & 3;

  unsigned xcd;
  asm volatile("s_getreg_b32 %0, hwreg(HW_REG_XCC_ID)" : "=s"(xcd));
  xcd &= 7u;

  unsigned* rank_slot = (unsigned*)&expart[0][0][0][0];
  if (tid == 0)
    *rank_slot = __hip_atomic_fetch_add(cntbase + 256 + xcd * 32, 1u,
                                        __ATOMIC_RELAXED, __HIP_MEMORY_SCOPE_AGENT);
  __syncthreads();
  const int rank = (int)(*rank_slot & 31u);
  __syncthreads();

  const int dt = rank;                 // gate-row tile [dt*64, dt*64+64)
  const int m0 = (int)xcd * 32;        // batch slice
  const int d0 = rank * 16;            // hidden-dim slice
  unsigned* cnt = cntbase + xcd * 32;  // per-XCD barrier counter

  // ---- preload weights ----
  #pragma unroll 4
  for (int i = 0; i < 16; ++i) {               // layer 0 -> LDS
    int G = tid + 512 * i;
    int r = G >> 7, g = G & 127;
    *(half8*)&wlds[r][(g ^ (r & 7)) * 8] =
        *(const half8*)(Wp + ((size_t)(dt * 64 + r)) * 1024 + g * 8);
  }
  half8 wreg[2][4][4];                         // layers 1,2: K=128 slice per wave
  #pragma unroll
  for (int ly = 0; ly < 2; ++ly)
    #pragma unroll
    for (int n = 0; n < 4; ++n)
      #pragma unroll
      for (int kk = 0; kk < 4; ++kk)
        wreg[ly][n][kk] = *(const half8*)(Wp +
          ((size_t)((ly + 1) * NH4 + dt * 64 + n * 16 + lr)) * 1024 + w * 128 + kk * 32 + lg * 8);

  const int di = tid & 15, cb = (tid >> 4) & 31;
  f32x4 breg4[3];                              // bias as gate-vector
  #pragma unroll
  for (int l = 0; l < 3; ++l)
    #pragma unroll
    for (int g = 0; g < 4; ++g)
      breg4[l][g] = bp[l * NH4 + dt * 64 + g * 16 + di];

  half8 bl0[2][4];   // l0 B-frags kk=0,1 held across the l2->l0 barrier (w<4)

  // ---- prologue: feat_p = feat@Wvis^T+bvis ; h0 = feat_p@Wvis^T+bvis ----
  {
    float* xb = &expart[0][0][0][0];
    const int wm2 = w & 1, wk = w >> 1;
    #pragma unroll 1
    for (int pg = 0; pg < 2; ++pg) {
      const _Float16* A = pg ? featp : feat16;
      half8 avp[4];
      #pragma unroll
      for (int kc = 0; kc < 4; ++kc)
        avp[kc] = l2_load(A + (size_t)(m0 + wm2 * 16 + lr) * ND + wk * 128 + kc * 32 + lg * 8);
      asm volatile("s_waitcnt vmcnt(0)" ::: "memory");
      __builtin_amdgcn_sched_barrier(0);
      f32x4 pacc = {0.f, 0.f, 0.f, 0.f};
      #pragma unroll
      for (int kc = 0; kc < 4; ++kc) {
        half8 bb = *(const half8*)(Wvis + (size_t)(d0 + lr) * ND + wk * 128 + kc * 32 + lg * 8);
        pacc = __builtin_amdgcn_mfma_f32_16x16x32_f16(avp[kc], bb, pacc, 0, 0, 0);
      }
      #pragma unroll
      for (int j = 0; j < 4; ++j)
        xb[wk * 512 + (wm2 * 16 + lg * 4 + j) * 16 + lr] = pacc[j];
      __syncthreads();
      {
        int m = tid >> 4, d = tid & 15;
        float v = xb[m * 16 + d] + xb[512 + m * 16 + d] + xb[1024 + m * 16 + d]
                + xb[1536 + m * 16 + d] + bvis[d0 + d];
        _Float16 hv = (_Float16)v;
        size_t off = (size_t)(m0 + m) * ND + d0 + d;
        if (pg == 0) featp[off] = hv;
        else {
          hbuf[(size_t)(0 * 2 + 1) * (NB * ND) + off] = hv;
          hbuf[(size_t)(1 * 2 + 1) * (NB * ND) + off] = hv;
          hbuf[(size_t)(2 * 2 + 1) * (NB * ND) + off] = hv;
        }
      }
      asm volatile("s_waitcnt vmcnt(0)" ::: "memory");
      xbar_core(cnt);
    }
  }

  // initial l0 B-frag prefetch for unit (0,0)
  if (w < 4) {
    #pragma unroll
    for (int kk = 0; kk < 2; ++kk)
      #pragma unroll
      for (int n = 0; n < 4; ++n) {
        int kg = w * 16 + kk * 4 + lg;
        bl0[kk][n] = *(const half8*)&wlds[n * 16 + lr][(kg ^ (lr & 7)) * 8];
      }
  }

  // ---- main recurrence: 603 units ----
  float cst[3] = {0.f, 0.f, 0.f};
  const size_t aoff0 = (size_t)(m0 + lr) * ND + (size_t)(w & 3) * 128 + lg * 8;
  const size_t aoff1 = aoff0 + (size_t)16 * ND;
  half8 av0[4], av1[4];

  #pragma unroll 1
  for (int t = 0; t < NT; ++t) {
    #pragma unroll
    for (int l = 0; l < 3; ++l) {
      const _Float16* xsrc = (l == 0)
        ? ((t == 0) ? x0 : hbuf + (size_t)(2 * 2 + ((t + 1) & 1)) * (NB * ND))
        : hbuf + (size_t)((l - 1) * 2 + (t & 1)) * (NB * ND);
      const _Float16* hsrc = hbuf + (size_t)(l * 2 + ((t + 1) & 1)) * (NB * ND);
      _Float16* hdst       = hbuf + (size_t)(l * 2 + (t & 1)) * (NB * ND);

      f32x4 acc[2][4];
      #pragma unroll
      for (int m = 0; m < 2; ++m)
        #pragma unroll
        for (int n = 0; n < 4; ++n)
          acc[m][n] = (f32x4){0.f, 0.f, 0.f, 0.f};

      if (w < 4) {
        // x-half: fresh, load post-barrier; staged tie-dep drains (r9).
        #pragma unroll
        for (int kk = 0; kk < 4; ++kk) {
          av0[kk] = l2_load(xsrc + aoff0 + kk * 32);
          av1[kk] = l2_load(xsrc + aoff1 + kk * 32);
        }
        asm volatile("s_waitcnt vmcnt(4)"
                     : "+v"(av0[0]), "+v"(av0[1]), "+v"(av1[0]), "+v"(av1[1]));
        __builtin_amdgcn_s_setprio(1);
        #pragma unroll
        for (int kk = 0; kk < 2; ++kk)
          #pragma unroll
          for (int n = 0; n < 4; ++n) {
            half8 bf = (l == 0) ? bl0[kk][n] : wreg[l - 1][n][kk];
            acc[0][n] = __builtin_amdgcn_mfma_f32_16x16x32_f16(av0[kk], bf, acc[0][n], 0, 0, 0);
            acc[1][n] = __builtin_amdgcn_mfma_f32_16x16x32_f16(av1[kk], bf, acc[1][n], 0, 0, 0);
          }
        __builtin_amdgcn_s_setprio(0);
        asm volatile("s_waitcnt vmcnt(0)"
                     : "+v"(av0[2]), "+v"(av0[3]), "+v"(av1[2]), "+v"(av1[3]));
        __builtin_amdgcn_s_setprio(1);
        #pragma unroll
        for (int kk = 2; kk < 4; ++kk)
          #pragma unroll
          for (int n = 0; n < 4; ++n) {
            half8 bf;
            if (l == 0) {
              int kg = w * 16 + kk * 4 + lg;
              bf = *(const half8*)&wlds[n * 16 + lr][(kg ^ (lr & 7)) * 8];
            } else bf = wreg[l - 1][n][kk];
            acc[0][n] = __builtin_amdgcn_mfma_f32_16x16x32_f16(av0[kk], bf, acc[0][n], 0, 0, 0);
            acc[1][n] = __builtin_amdgcn_mfma_f32_16x16x32_f16(av1[kk], bf, acc[1][n], 0, 0, 0);
          }
        __builtin_amdgcn_s_setprio(0);
      } else {
        if (t == 0 && l == 0) {        // first unit: h0 not prefetched
          #pragma unroll
          for (int kk = 0; kk < 4; ++kk) {
            av0[kk] = l2_load(hsrc + aoff0 + kk * 32);
            av1[kk] = l2_load(hsrc + aoff1 + kk * 32);
          }
        }
        asm volatile("s_waitcnt vmcnt(0)"
                     : "+v"(av0[0]), "+v"(av0[1]), "+v"(av0[2]), "+v"(av0[3]),
                       "+v"(av1[0]), "+v"(av1[1]), "+v"(av1[2]), "+v"(av1[3]));
        __builtin_amdgcn_s_setprio(1);
        #pragma unroll
        for (int kk = 0; kk < 4; ++kk)
          #pragma unroll
          for (int n = 0; n < 4; ++n) {
            half8 bf;
            if (l == 0) {
              int kg = w * 16 + kk * 4 + lg;
              bf = *(const half8*)&wlds[n * 16 + lr][(kg ^ (lr & 7)) * 8];
            } else bf = wreg[l - 1][n][kk];
            acc[0][n] = __builtin_amdgcn_mfma_f32_16x16x32_f16(av0[kk], bf, acc[0][n], 0, 0, 0);
            acc[1][n] = __builtin_amdgcn_mfma_f32_16x16x32_f16(av1[kk], bf, acc[1][n], 0, 0, 0);
          }
        __builtin_amdgcn_s_setprio(0);
      }

      // ---- exchange, gate-transposed: [slice][batch][di][gate] ----
      if (w >= 4) {
        #pragma unroll
        for (int m = 0; m < 2; ++m)
          #pragma unroll
          for (int j = 0; j < 4; ++j) {
            f32x4 v = {acc[m][0][j], acc[m][1][j], acc[m][2][j], acc[m][3][j]};
            *(f32x4*)&expart[w - 4][m * 16 + lg * 4 + j][lr][0] = v;
          }
      }
      __syncthreads();
      if (w < 4) {
        #pragma unroll
        for (int m = 0; m < 2; ++m)
          #pragma unroll
          for (int j = 0; j < 4; ++j) {
            f32x4* pp = (f32x4*)&expart[w][m * 16 + lg * 4 + j][lr][0];
            f32x4 tv = *pp;
            tv[0] += acc[m][0][j]; tv[1] += acc[m][1][j];
            tv[2] += acc[m][2][j]; tv[3] += acc[m][3][j];
            *pp = tv;
          }
      }
      __syncthreads();

      // ---- cell update: one cell per thread; gather = 4x ds_read_b128 ----
      {
        f32x4 s4 = breg4[l];
        #pragma unroll
        for (int s = 0; s < 4; ++s) {
          f32x4 g = *(const f32x4*)&expart[s][cb][di][0];
          s4 += g;
        }
        float c = cst[l];
        c = sigf(s4[1]) * c + sigf(s4[0]) * tanh_(s4[2]);
        cst[l] = c;
        _Float16 hv = (_Float16)(sigf(s4[3]) * tanh_(c));
        size_t off = (size_t)(m0 + cb) * ND + d0 + di;
        hdst[off] = hv;                        // h store FIRST (drained at release)
        if (l == 2) {                          // res store SECOND via ordered asm:
          unsigned hw = (unsigned)__builtin_bit_cast(unsigned short, hv);
          _Float16* rp = res + (size_t)t * (NB * ND) + off;
          asm volatile("global_store_short %0, %1, off"
                       :: "v"(rp), "v"(hw) : "memory");
        }
      }

      if (!(t == NT - 1 && l == 2)) {
        if (w >= 4) {                    // prefetch next unit's h-half (2 barriers old)
          const int nt2 = (l == 2) ? t + 1 : t;
          const int nl  = (l == 2) ? 0 : l + 1;
          const _Float16* nh = hbuf + (size_t)(nl * 2 + ((nt2 + 1) & 1)) * (NB * ND);
          #pragma unroll
          for (int kk = 0; kk < 4; ++kk) {
            av0[kk] = l2_load(nh + aoff0 + kk * 32);
            av1[kk] = l2_load(nh + aoff1 + kk * 32);
          }
        } else if (l == 2) {             // w<4: prefetch l0 B-frags for next unit
          #pragma unroll
          for (int kk = 0; kk < 2; ++kk)
            #pragma unroll
            for (int n = 0; n < 4; ++n) {
              int kg = w * 16 + kk * 4 + lg;
              bl0[kk][n] = *(const half8*)&wlds[n * 16 + lr][(kg ^ (lr & 7)) * 8];
            }
        }
        // release drain: h must be L2-visible; res (l==2) and prefetch loads
        // stay in flight (vmcnt drains oldest-first, m135).
        if (l == 2) {
          if (w >= 4) asm volatile("s_waitcnt vmcnt(9)" ::: "memory");
          else        asm volatile("s_waitcnt vmcnt(1)" ::: "memory");
        } else {
          if (w >= 4) asm volatile("s_waitcnt vmcnt(8)" ::: "memory");
          else        asm volatile("s_waitcnt vmcnt(0)" ::: "memory");
        }
        xbar_core(cnt);
      }
      // last unit: stream order publishes res to the head kernel
    }
  }
}

// ---------------- fused MLP head (unchanged) ----------------
__global__ __launch_bounds__(256, 2) void head_kernel(
    const _Float16* __restrict__ res,  // [51456][512]
    const _Float16* __restrict__ W1h,  // [1024][512]
    const float* __restrict__ b1,      // [1024]
    const _Float16* __restrict__ W2h,  // [128][1024]
    const float* __restrict__ b2,      // [128]
    float* __restrict__ out) {         // [256][128][201]
  const int tile = blockIdx.x;         // 0..803
  const int tid = threadIdx.x;
  const int lane = tid & 63, w = tid >> 6;
  const int lr = lane & 15, lg = lane >> 4;
  const int r0 = tile * 64;

  __shared__ _Float16 mid[64][128];    // XOR-swizzled 16B blocks

  f32x4 acc2[8];
  #pragma unroll
  for (int n = 0; n < 8; ++n) acc2[n] = (f32x4){0.f, 0.f, 0.f, 0.f};

  const size_t arow = (size_t)(r0 + w * 16 + lr) * ND;

  #pragma unroll 1
  for (int nc = 0; nc < 8; ++nc) {
    f32x4 acc1[8];
    #pragma unroll
    for (int n = 0; n < 8; ++n) acc1[n] = (f32x4){0.f, 0.f, 0.f, 0.f};
    #pragma unroll 2
    for (int kc = 0; kc < 16; ++kc) {
      half8 a = *(const half8*)(res + arow + kc * 32 + lg * 8);
      #pragma unroll
      for (int n = 0; n < 8; ++n) {
        half8 bb = *(const half8*)(W1h + (size_t)(nc * 128 + n * 16 + lr) * ND + kc * 32 + lg * 8);
        acc1[n] = __builtin_amdgcn_mfma_f32_16x16x32_f16(a, bb, acc1[n], 0, 0, 0);
      }
    }
    __syncthreads();   // previous chunk's mid reads done
    #pragma unroll
    for (int n = 0; n < 8; ++n) {
      #pragma unroll
      for (int j = 0; j < 4; ++j) {
        int m = w * 16 + lg * 4 + j;
        int col = n * 16 + lr;
        float v = acc1[n][j] + b1[nc * 128 + col];
        v = 0.5f * v * (1.0f + erff(v * 0.7071067811865475f));   // exact gelu
        int sw = (((col >> 3) ^ (m & 15)) << 3) + (col & 7);
        mid[m][sw] = (_Float16)v;
      }
    }
    __syncthreads();
    #pragma unroll
    for (int kc2 = 0; kc2 < 4; ++kc2) {
      int row = w * 16 + lr;
      int blk = (kc2 * 4 + lg) ^ (row & 15);
      half8 a2 = *(const half8*)(&mid[row][blk * 8]);
      #pragma unroll
      for (int n = 0; n < 8; ++n) {
        half8 bb = *(const half8*)(W2h + (size_t)(n * 16 + lr) * NMID + nc * 128 + kc2 * 32 + lg * 8);
        acc2[n] = __builtin_amdgcn_mfma_f32_16x16x32_f16(a2, bb, acc2[n], 0, 0, 0);
      }
    }
  }
  #pragma unroll
  for (int n = 0; n < 8; ++n) {
    #pragma unroll
    for (int j = 0; j < 4; ++j) {
      int r = r0 + w * 16 + lg * 4 + j;
      int b = r & 255, t = r >> 8;     // rows are r = t*256 + b
      int v = n * 16 + lr;
      out[((size_t)b * NV + v) * NT + t] = acc2[n][j] + b2[v];
    }
  }
}

// ---------------- launch ----------------
extern "C" void kernel_launch(void* const* d_in, const int* in_sizes, int n_in,
                              void* d_out, int out_size, void* d_ws, size_t ws_size,
                              hipStream_t stream) {
  const float* feat  = (const float*)d_in[0];
  const float* Wvis  = (const float*)d_in[1];
  const float* bvis  = (const float*)d_in[2];
  const float* embed = (const float*)d_in[3];
  const float* Wih   = (const float*)d_in[4];
  const float* Whh   = (const float*)d_in[5];
  const float* bih   = (const float*)d_in[6];
  const float* bhh   = (const float*)d_in[7];
  const float* W1    = (const float*)d_in[8];
  const float* b1    = (const float*)d_in[9];
  const float* W2    = (const float*)d_in[10];
  const float* b2    = (const float*)d_in[11];
  float* out = (float*)d_out;

  char* p = (char*)d_ws;
  _Float16* Wp     = (_Float16*)p; p += (size_t)NL * NH4 * 1024 * 2;   // 12.58 MB
  _Float16* Wvis16 = (_Float16*)p; p += (size_t)512 * 512 * 2;
  _Float16* feat16 = (_Float16*)p; p += (size_t)256 * 512 * 2;
  _Float16* x0     = (_Float16*)p; p += (size_t)256 * 512 * 2;
  _Float16* featp  = (_Float16*)p; p += (size_t)256 * 512 * 2;
  _Float16* hbuf   = (_Float16*)p; p += (size_t)NL * 2 * NB * ND * 2;
  _Float16* resb   = (_Float16*)p; p += (size_t)NT * NB * ND * 2;      // 52.7 MB
  _Float16* W1h    = (_Float16*)p; p += (size_t)NMID * ND * 2;
  _Float16* W2h    = (_Float16*)p; p += (size_t)NV * NMID * 2;
  float*    bp     = (float*)p;    p += (size_t)NL * NH4 * 4;
  unsigned* cnt    = (unsigned*)p; p += 4096;   // [0..255] barriers, [256..511] ranks

  prep_all<<<24576, 256, 0, stream>>>(Wih, Whh, bih, bhh, Wvis, feat, embed, W1, W2,
                                      Wp, bp, Wvis16, feat16, x0, W1h, W2h, cnt);
  lstm_persist<<<256, 512, 0, stream>>>(Wp, bp, Wvis16, bvis, feat16, x0,
                                        featp, hbuf, resb, cnt);
  head_kernel<<<804, 256, 0, stream>>>(resb, W1h, b1, W2h, b2, out);
  (void)in_sizes; (void)n_in; (void)out_size; (void)ws_size;
}

// Round 12
// 3231.939 us; speedup vs baseline: 1.0087x; 1.0087x over previous
//
#include <hip/hip_runtime.h>

#define NB   256
#define ND   512
#define NH4  2048
#define NL   3
#define NT   201
#define NV   128
#define NMID 1024

typedef _Float16 half8 __attribute__((ext_vector_type(8)));
typedef float f32x4 __attribute__((ext_vector_type(4)));

__device__ __forceinline__ float sigf(float x) { return 1.0f / (1.0f + __expf(-x)); }
__device__ __forceinline__ float tanh_(float x) {
  float e = __expf(-2.0f * fabsf(x));
  float t = (1.0f - e) / (1.0f + e);
  return x < 0.0f ? -t : t;
}

// 16B load issued to L2 (sc0); freshness ensured by the single buffer_inv at
// barrier exit (sc0 alone does NOT bypass L1 - r3 lesson).
__device__ __forceinline__ half8 l2_load(const _Float16* p) {
  half8 v;
  asm volatile("global_load_dwordx4 %0, %1, off sc0" : "=v"(v) : "v"(p));
  return v;
}

// Genuine atomic RMW at the issuing XCD's L2 (r5-proven). ~300cy round trip.
__device__ __forceinline__ unsigned l2_rmw_add(unsigned* p, unsigned val) {
  unsigned v;
  asm volatile("global_atomic_add %0, %1, %2, off sc0\n\ts_waitcnt vmcnt(0)"
               : "=v"(v) : "v"(p), "v"(val) : "memory");
  return v;
}

// XCD-local leader/flag barrier (r12). Arrival: ONE increment RMW per WG on
// the shared counter (no loop). Discovery: ONLY rank0 polls the counter
// (single poller, no same-line contention); it then publishes the epoch to 31
// per-WG flag words, each on its OWN 128B line; each follower RMW-polls its
// own line (1 poller/line -> parallel in L2). Monotonic epochs, no resets.
// buffer_inv exactly ONCE at exit (r6 lesson). Release ordering: flag==ep
// implies leader saw cnt==32*ep implies every WG's pre-arrive drain is done.
// pref=true: waves 4..7 entered with 8 prefetch loads in flight issued AFTER
// their stores; vmcnt(8) drains exactly the stores (release) while the loads
// fly through the barrier wait. Bounded spins -> wrong answer, not hang.
__device__ __forceinline__ void xbar(unsigned* cnt, unsigned* flagbase, int rank,
                                     unsigned ep, bool pref) {
  if (pref && threadIdx.x >= 256)
    asm volatile("s_waitcnt vmcnt(8)" ::: "memory");
  else
    asm volatile("s_waitcnt vmcnt(0)" ::: "memory");
  __syncthreads();
  if (threadIdx.x == 0) {
    l2_rmw_add(cnt, 1u);                       // arrive (single RMW, no loop)
    if (rank == 0) {
      unsigned target = 32u * ep;
      int guard = 1 << 16;
      while (l2_rmw_add(cnt, 0u) < target && --guard)
        __builtin_amdgcn_s_sleep(1);
      #pragma unroll 4
      for (int r = 1; r < 32; ++r)             // publish epoch, one line per WG
        asm volatile("global_store_dword %0, %1, off sc0"
                     :: "v"(flagbase + r * 32), "v"(ep) : "memory");
    } else {
      unsigned* myflag = flagbase + rank * 32;
      int guard = 1 << 16;
      while (l2_rmw_add(myflag, 0u) < ep && --guard)
        __builtin_amdgcn_s_sleep(1);
    }
  }
  __syncthreads();
  asm volatile("buffer_inv" ::: "memory");     // L1-only invalidate, once
  __builtin_amdgcn_sched_barrier(0);
}

// ---------------- fused prep kernel ----------------
__global__ void prep_all(const float* __restrict__ Wih, const float* __restrict__ Whh,
                         const float* __restrict__ bih, const float* __restrict__ bhh,
                         const float* __restrict__ Wvis, const float* __restrict__ feat,
                         const float* __restrict__ embed, const float* __restrict__ W1,
                         const float* __restrict__ W2,
                         _Float16* __restrict__ Wp, float* __restrict__ bp,
                         _Float16* __restrict__ Wvis16, _Float16* __restrict__ feat16,
                         _Float16* __restrict__ x0, _Float16* __restrict__ W1h,
                         _Float16* __restrict__ W2h, unsigned* __restrict__ cnt) {
  size_t idx = (size_t)blockIdx.x * 256 + threadIdx.x;   // 3*2048*1024 total
  {
    int k = (int)(idx & 1023);
    int R = (int)((idx >> 10) & 2047);
    int l = (int)(idx >> 21);
    int dt = R >> 6, g = (R >> 4) & 3, di = R & 15;
    int col = g * 512 + dt * 16 + di;
    float v = (k < 512) ? Wih[((size_t)l * NH4 + col) * ND + k]
                        : Whh[((size_t)l * NH4 + col) * ND + (k - 512)];
    Wp[idx] = (_Float16)v;
  }
  if (idx < (size_t)NL * NH4) {
    int R = (int)(idx & 2047);
    int l = (int)(idx >> 11);
    int dt = R >> 6, g = (R >> 4) & 3, di = R & 15;
    int col = g * 512 + dt * 16 + di;
    bp[idx] = bih[l * NH4 + col] + bhh[l * NH4 + col];
  }
  if (idx < 512 * 512)  Wvis16[idx] = (_Float16)Wvis[idx];
  if (idx < 256 * 512)  feat16[idx] = (_Float16)feat[idx];
  if (idx < 256 * 512)  x0[idx]     = (_Float16)embed[idx & 511];   // embed[START_IDX=0]
  if (idx < 1024 * 512) W1h[idx]    = (_Float16)W1[idx];
  if (idx < 128 * 1024) W2h[idx]    = (_Float16)W2[idx];
  if (idx < 16384) cnt[idx] = 0;     // counters + ranks + per-WG flags
}

// ---------------- persistent LSTM kernel ----------------
// r10 structure (proven 2105us): 256 WGs x 512 threads, 160KB LDS -> 1 WG/CU
// -> 32 WGs/XCD, 2 waves/SIMD. K split 8 ways: waves 0-3 x-half, 4-7 h-half.
// Layer-0 weights in LDS, layers 1-2 in registers. Gate-transposed exchange.
// r12: ONLY change vs r10 = leader/per-WG-flag barrier (kills same-line RMW
// poll contention).
__global__ __launch_bounds__(512, 2) void lstm_persist(
    const _Float16* __restrict__ Wp,     // [3][2048][1024] permuted
    const float* __restrict__ bp,        // [3][2048]
    const _Float16* __restrict__ Wvis,   // [512][512]
    const float* __restrict__ bvis,      // [512]
    const _Float16* __restrict__ feat16, // [256][512]
    const _Float16* __restrict__ x0,     // [256][512]
    _Float16* __restrict__ featp,        // [256][512]
    _Float16* __restrict__ hbuf,         // [3][2][256][512]
    _Float16* __restrict__ res,          // [201][256][512]
    unsigned* __restrict__ cntbase) {
  __shared__ _Float16 wlds[64][1024];          // 128KB layer-0 weights
  __shared__ float expart[4][32][16][4];       // 32KB: [slice][batch][di][gate]
  // total LDS = 163840 B exactly (gfx950 per-WG limit)

  const int tid = threadIdx.x;
  const int lane = tid & 63, w = tid >> 6;     // w = 0..7
  const int lr = lane & 15, lg = (lane >> 4) & 3;

  unsigned xcd;
  asm volatile("s_getreg_b32 %0, hwreg(HW_REG_XCC_ID)" : "=s"(xcd));
  xcd &= 7u;

  unsigned* rank_slot = (unsigned*)&expart[0][0][0][0];
  if (tid == 0)
    *rank_slot = __hip_atomic_fetch_add(cntbase + 256 + xcd * 32, 1u,
                                        __ATOMIC_RELAXED, __HIP_MEMORY_SCOPE_AGENT);
  __syncthreads();
  const int rank = (int)(*rank_slot & 31u);
  __syncthreads();

  const int dt = rank;                 // gate-row tile [dt*64, dt*64+64)
  const int m0 = (int)xcd * 32;        // batch slice
  const int d0 = rank * 16;            // hidden-dim slice
  unsigned* cnt      = cntbase + xcd * 32;             // per-XCD counter line
  unsigned* flagbase = cntbase + 1024 + xcd * 1024;    // 32 flags x 128B lines
  unsigned ep = 0;

  // ---- preload weights ----
  #pragma unroll 4
  for (int i = 0; i < 16; ++i) {               // layer 0 -> LDS
    int G = tid + 512 * i;
    int r = G >> 7, g = G & 127;
    *(half8*)&wlds[r][(g ^ (r & 7)) * 8] =
        *(const half8*)(Wp + ((size_t)(dt * 64 + r)) * 1024 + g * 8);
  }
  half8 wreg[2][4][4];                         // layers 1,2: K=128 slice per wave
  #pragma unroll
  for (int ly = 0; ly < 2; ++ly)
    #pragma unroll
    for (int n = 0; n < 4; ++n)
      #pragma unroll
      for (int kk = 0; kk < 4; ++kk)
        wreg[ly][n][kk] = *(const half8*)(Wp +
          ((size_t)((ly + 1) * NH4 + dt * 64 + n * 16 + lr)) * 1024 + w * 128 + kk * 32 + lg * 8);

  const int di = tid & 15, cb = (tid >> 4) & 31;
  f32x4 breg4[3];                              // bias as gate-vector
  #pragma unroll
  for (int l = 0; l < 3; ++l)
    #pragma unroll
    for (int g = 0; g < 4; ++g)
      breg4[l][g] = bp[l * NH4 + dt * 64 + g * 16 + di];

  // ---- prologue: feat_p = feat@Wvis^T+bvis ; h0 = feat_p@Wvis^T+bvis ----
  {
    float* xb = &expart[0][0][0][0];
    const int wm2 = w & 1, wk = w >> 1;
    #pragma unroll 1
    for (int pg = 0; pg < 2; ++pg) {
      const _Float16* A = pg ? featp : feat16;
      half8 avp[4];
      #pragma unroll
      for (int kc = 0; kc < 4; ++kc)
        avp[kc] = l2_load(A + (size_t)(m0 + wm2 * 16 + lr) * ND + wk * 128 + kc * 32 + lg * 8);
      asm volatile("s_waitcnt vmcnt(0)" ::: "memory");
      __builtin_amdgcn_sched_barrier(0);
      f32x4 pacc = {0.f, 0.f, 0.f, 0.f};
      #pragma unroll
      for (int kc = 0; kc < 4; ++kc) {
        half8 bb = *(const half8*)(Wvis + (size_t)(d0 + lr) * ND + wk * 128 + kc * 32 + lg * 8);
        pacc = __builtin_amdgcn_mfma_f32_16x16x32_f16(avp[kc], bb, pacc, 0, 0, 0);
      }
      #pragma unroll
      for (int j = 0; j < 4; ++j)
        xb[wk * 512 + (wm2 * 16 + lg * 4 + j) * 16 + lr] = pacc[j];
      __syncthreads();
      {
        int m = tid >> 4, d = tid & 15;
        float v = xb[m * 16 + d] + xb[512 + m * 16 + d] + xb[1024 + m * 16 + d]
                + xb[1536 + m * 16 + d] + bvis[d0 + d];
        _Float16 hv = (_Float16)v;
        size_t off = (size_t)(m0 + m) * ND + d0 + d;
        if (pg == 0) featp[off] = hv;
        else {
          hbuf[(size_t)(0 * 2 + 1) * (NB * ND) + off] = hv;
          hbuf[(size_t)(1 * 2 + 1) * (NB * ND) + off] = hv;
          hbuf[(size_t)(2 * 2 + 1) * (NB * ND) + off] = hv;
        }
      }
      xbar(cnt, flagbase, rank, ++ep, false);
    }
  }

  // ---- main recurrence: 603 units ----
  float cst[3] = {0.f, 0.f, 0.f};
  const size_t aoff0 = (size_t)(m0 + lr) * ND + (size_t)(w & 3) * 128 + lg * 8;
  const size_t aoff1 = aoff0 + (size_t)16 * ND;
  half8 av0[4], av1[4];

  #pragma unroll 1
  for (int t = 0; t < NT; ++t) {
    #pragma unroll
    for (int l = 0; l < 3; ++l) {
      const _Float16* xsrc = (l == 0)
        ? ((t == 0) ? x0 : hbuf + (size_t)(2 * 2 + ((t + 1) & 1)) * (NB * ND))
        : hbuf + (size_t)((l - 1) * 2 + (t & 1)) * (NB * ND);
      const _Float16* hsrc = hbuf + (size_t)(l * 2 + ((t + 1) & 1)) * (NB * ND);
      _Float16* hdst       = hbuf + (size_t)(l * 2 + (t & 1)) * (NB * ND);

      f32x4 acc[2][4];
      #pragma unroll
      for (int m = 0; m < 2; ++m)
        #pragma unroll
        for (int n = 0; n < 4; ++n)
          acc[m][n] = (f32x4){0.f, 0.f, 0.f, 0.f};

      if (w < 4) {
        // x-half: fresh, load post-barrier; staged tie-dep drains (r9).
        #pragma unroll
        for (int kk = 0; kk < 4; ++kk) {
          av0[kk] = l2_load(xsrc + aoff0 + kk * 32);
          av1[kk] = l2_load(xsrc + aoff1 + kk * 32);
        }
        asm volatile("s_waitcnt vmcnt(4)"
                     : "+v"(av0[0]), "+v"(av0[1]), "+v"(av1[0]), "+v"(av1[1]));
        __builtin_amdgcn_s_setprio(1);
        #pragma unroll
        for (int kk = 0; kk < 2; ++kk)
          #pragma unroll
          for (int n = 0; n < 4; ++n) {
            half8 bf;
            if (l == 0) {
              int kg = w * 16 + kk * 4 + lg;
              bf = *(const half8*)&wlds[n * 16 + lr][(kg ^ (lr & 7)) * 8];
            } else bf = wreg[l - 1][n][kk];
            acc[0][n] = __builtin_amdgcn_mfma_f32_16x16x32_f16(av0[kk], bf, acc[0][n], 0, 0, 0);
            acc[1][n] = __builtin_amdgcn_mfma_f32_16x16x32_f16(av1[kk], bf, acc[1][n], 0, 0, 0);
          }
        __builtin_amdgcn_s_setprio(0);
        asm volatile("s_waitcnt vmcnt(0)"
                     : "+v"(av0[2]), "+v"(av0[3]), "+v"(av1[2]), "+v"(av1[3]));
        __builtin_amdgcn_s_setprio(1);
        #pragma unroll
        for (int kk = 2; kk < 4; ++kk)
          #pragma unroll
          for (int n = 0; n < 4; ++n) {
            half8 bf;
            if (l == 0) {
              int kg = w * 16 + kk * 4 + lg;
              bf = *(const half8*)&wlds[n * 16 + lr][(kg ^ (lr & 7)) * 8];
            } else bf = wreg[l - 1][n][kk];
            acc[0][n] = __builtin_amdgcn_mfma_f32_16x16x32_f16(av0[kk], bf, acc[0][n], 0, 0, 0);
            acc[1][n] = __builtin_amdgcn_mfma_f32_16x16x32_f16(av1[kk], bf, acc[1][n], 0, 0, 0);
          }
        __builtin_amdgcn_s_setprio(0);
      } else {
        if (t == 0 && l == 0) {        // first unit: h0 not prefetched
          #pragma unroll
          for (int kk = 0; kk < 4; ++kk) {
            av0[kk] = l2_load(hsrc + aoff0 + kk * 32);
            av1[kk] = l2_load(hsrc + aoff1 + kk * 32);
          }
        }
        asm volatile("s_waitcnt vmcnt(0)"
                     : "+v"(av0[0]), "+v"(av0[1]), "+v"(av0[2]), "+v"(av0[3]),
                       "+v"(av1[0]), "+v"(av1[1]), "+v"(av1[2]), "+v"(av1[3]));
        __builtin_amdgcn_s_setprio(1);
        #pragma unroll
        for (int kk = 0; kk < 4; ++kk)
          #pragma unroll
          for (int n = 0; n < 4; ++n) {
            half8 bf;
            if (l == 0) {
              int kg = w * 16 + kk * 4 + lg;
              bf = *(const half8*)&wlds[n * 16 + lr][(kg ^ (lr & 7)) * 8];
            } else bf = wreg[l - 1][n][kk];
            acc[0][n] = __builtin_amdgcn_mfma_f32_16x16x32_f16(av0[kk], bf, acc[0][n], 0, 0, 0);
            acc[1][n] = __builtin_amdgcn_mfma_f32_16x16x32_f16(av1[kk], bf, acc[1][n], 0, 0, 0);
          }
        __builtin_amdgcn_s_setprio(0);
      }

      // ---- exchange, gate-transposed: [slice][batch][di][gate] ----
      if (w >= 4) {
        #pragma unroll
        for (int m = 0; m < 2; ++m)
          #pragma unroll
          for (int j = 0; j < 4; ++j) {
            f32x4 v = {acc[m][0][j], acc[m][1][j], acc[m][2][j], acc[m][3][j]};
            *(f32x4*)&expart[w - 4][m * 16 + lg * 4 + j][lr][0] = v;
          }
      }
      __syncthreads();
      if (w < 4) {
        #pragma unroll
        for (int m = 0; m < 2; ++m)
          #pragma unroll
          for (int j = 0; j < 4; ++j) {
            f32x4* pp = (f32x4*)&expart[w][m * 16 + lg * 4 + j][lr][0];
            f32x4 tv = *pp;
            tv[0] += acc[m][0][j]; tv[1] += acc[m][1][j];
            tv[2] += acc[m][2][j]; tv[3] += acc[m][3][j];
            *pp = tv;
          }
      }
      __syncthreads();

      // ---- cell update: one cell per thread; gather = 4x ds_read_b128 ----
      {
        f32x4 s4 = breg4[l];
        #pragma unroll
        for (int s = 0; s < 4; ++s) {
          f32x4 g = *(const f32x4*)&expart[s][cb][di][0];
          s4 += g;
        }
        float c = cst[l];
        c = sigf(s4[1]) * c + sigf(s4[0]) * tanh_(s4[2]);
        cst[l] = c;
        _Float16 hv = (_Float16)(sigf(s4[3]) * tanh_(c));
        size_t off = (size_t)(m0 + cb) * ND + d0 + di;
        hdst[off] = hv;
        if (l == 2) res[(size_t)t * (NB * ND) + off] = hv;
      }

      if (!(t == NT - 1 && l == 2)) {
        if (w >= 4) {                    // prefetch next unit's h-half (2 barriers old)
          const int nt2 = (l == 2) ? t + 1 : t;
          const int nl  = (l == 2) ? 0 : l + 1;
          const _Float16* nh = hbuf + (size_t)(nl * 2 + ((nt2 + 1) & 1)) * (NB * ND);
          #pragma unroll
          for (int kk = 0; kk < 4; ++kk) {
            av0[kk] = l2_load(nh + aoff0 + kk * 32);
            av1[kk] = l2_load(nh + aoff1 + kk * 32);
          }
        }
        xbar(cnt, flagbase, rank, ++ep, true);
      }
      // last unit: stream order publishes res to the head kernel
    }
  }
}

// ---------------- fused MLP head (unchanged) ----------------
__global__ __launch_bounds__(256, 2) void head_kernel(
    const _Float16* __restrict__ res,  // [51456][512]
    const _Float16* __restrict__ W1h,  // [1024][512]
    const float* __restrict__ b1,      // [1024]
    const _Float16* __restrict__ W2h,  // [128][1024]
    const float* __restrict__ b2,      // [128]
    float* __restrict__ out) {         // [256][128][201]
  const int tile = blockIdx.x;         // 0..803
  const int tid = threadIdx.x;
  const int lane = tid & 63, w = tid >> 6;
  const int lr = lane & 15, lg = lane >> 4;
  const int r0 = tile * 64;

  __shared__ _Float16 mid[64][128];    // XOR-swizzled 16B blocks

  f32x4 acc2[8];
  #pragma unroll
  for (int n = 0; n < 8; ++n) acc2[n] = (f32x4){0.f, 0.f, 0.f, 0.f};

  const size_t arow = (size_t)(r0 + w * 16 + lr) * ND;

  #pragma unroll 1
  for (int nc = 0; nc < 8; ++nc) {
    f32x4 acc1[8];
    #pragma unroll
    for (int n = 0; n < 8; ++n) acc1[n] = (f32x4){0.f, 0.f, 0.f, 0.f};
    #pragma unroll 2
    for (int kc = 0; kc < 16; ++kc) {
      half8 a = *(const half8*)(res + arow + kc * 32 + lg * 8);
      #pragma unroll
      for (int n = 0; n < 8; ++n) {
        half8 bb = *(const half8*)(W1h + (size_t)(nc * 128 + n * 16 + lr) * ND + kc * 32 + lg * 8);
        acc1[n] = __builtin_amdgcn_mfma_f32_16x16x32_f16(a, bb, acc1[n], 0, 0, 0);
      }
    }
    __syncthreads();   // previous chunk's mid reads done
    #pragma unroll
    for (int n = 0; n < 8; ++n) {
      #pragma unroll
      for (int j = 0; j < 4; ++j) {
        int m = w * 16 + lg * 4 + j;
        int col = n * 16 + lr;
        float v = acc1[n][j] + b1[nc * 128 + col];
        v = 0.5f * v * (1.0f + erff(v * 0.7071067811865475f));   // exact gelu
        int sw = (((col >> 3) ^ (m & 15)) << 3) + (col & 7);
        mid[m][sw] = (_Float16)v;
      }
    }
    __syncthreads();
    #pragma unroll
    for (int kc2 = 0; kc2 < 4; ++kc2) {
      int row = w * 16 + lr;
      int blk = (kc2 * 4 + lg) ^ (row & 15);
      half8 a2 = *(const half8*)(&mid[row][blk * 8]);
      #pragma unroll
      for (int n = 0; n < 8; ++n) {
        half8 bb = *(const half8*)(W2h + (size_t)(n * 16 + lr) * NMID + nc * 128 + kc2 * 32 + lg * 8);
        acc2[n] = __builtin_amdgcn_mfma_f32_16x16x32_f16(a2, bb, acc2[n], 0, 0, 0);
      }
    }
  }
  #pragma unroll
  for (int n = 0; n < 8; ++n) {
    #pragma unroll
    for (int j = 0; j < 4; ++j) {
      int r = r0 + w * 16 + lg * 4 + j;
      int b = r & 255, t = r >> 8;     // rows are r = t*256 + b
      int v = n * 16 + lr;
      out[((size_t)b * NV + v) * NT + t] = acc2[n][j] + b2[v];
    }
  }
}

// ---------------- launch ----------------
extern "C" void kernel_launch(void* const* d_in, const int* in_sizes, int n_in,
                              void* d_out, int out_size, void* d_ws, size_t ws_size,
                              hipStream_t stream) {
  const float* feat  = (const float*)d_in[0];
  const float* Wvis  = (const float*)d_in[1];
  const float* bvis  = (const float*)d_in[2];
  const float* embed = (const float*)d_in[3];
  const float* Wih   = (const float*)d_in[4];
  const float* Whh   = (const float*)d_in[5];
  const float* bih   = (const float*)d_in[6];
  const float* bhh   = (const float*)d_in[7];
  const float* W1    = (const float*)d_in[8];
  const float* b1    = (const float*)d_in[9];
  const float* W2    = (const float*)d_in[10];
  const float* b2    = (const float*)d_in[11];
  float* out = (float*)d_out;

  char* p = (char*)d_ws;
  _Float16* Wp     = (_Float16*)p; p += (size_t)NL * NH4 * 1024 * 2;   // 12.58 MB
  _Float16* Wvis16 = (_Float16*)p; p += (size_t)512 * 512 * 2;
  _Float16* feat16 = (_Float16*)p; p += (size_t)256 * 512 * 2;
  _Float16* x0     = (_Float16*)p; p += (size_t)256 * 512 * 2;
  _Float16* featp  = (_Float16*)p; p += (size_t)256 * 512 * 2;
  _Float16* hbuf   = (_Float16*)p; p += (size_t)NL * 2 * NB * ND * 2;
  _Float16* resb   = (_Float16*)p; p += (size_t)NT * NB * ND * 2;      // 52.7 MB
  _Float16* W1h    = (_Float16*)p; p += (size_t)NMID * ND * 2;
  _Float16* W2h    = (_Float16*)p; p += (size_t)NV * NMID * 2;
  float*    bp     = (float*)p;    p += (size_t)NL * NH4 * 4;
  unsigned* cnt    = (unsigned*)p; p += 65536;
  // cnt layout (words): [0..255] barrier counters (xcd*32), [256..511] ranks,
  // [1024..9215] per-WG flags (xcd*1024 + rank*32; one 128B line per WG)

  prep_all<<<24576, 256, 0, stream>>>(Wih, Whh, bih, bhh, Wvis, feat, embed, W1, W2,
                                      Wp, bp, Wvis16, feat16, x0, W1h, W2h, cnt);
  lstm_persist<<<256, 512, 0, stream>>>(Wp, bp, Wvis16, bvis, feat16, x0,
                                        featp, hbuf, resb, cnt);
  head_kernel<<<804, 256, 0, stream>>>(resb, W1h, b1, W2h, b2, out);
  (void)in_sizes; (void)n_in; (void)out_size; (void)ws_size;
}

// Round 13
// 2359.150 us; speedup vs baseline: 1.3818x; 1.3700x over previous
//
#include <hip/hip_runtime.h>

#define NB   256
#define ND   512
#define NH4  2048
#define NL   3
#define NT   201
#define NV   128
#define NMID 1024

typedef _Float16 half8 __attribute__((ext_vector_type(8)));
typedef float f32x4 __attribute__((ext_vector_type(4)));

__device__ __forceinline__ float sigf(float x) { return 1.0f / (1.0f + __expf(-x)); }
__device__ __forceinline__ float tanh_(float x) {
  float e = __expf(-2.0f * fabsf(x));
  float t = (1.0f - e) / (1.0f + e);
  return x < 0.0f ? -t : t;
}

// 16B load issued to L2 (sc0); freshness ensured by the single buffer_inv at
// barrier exit (sc0 alone does NOT bypass L1 - r3 lesson).
__device__ __forceinline__ half8 l2_load(const _Float16* p) {
  half8 v;
  asm volatile("global_load_dwordx4 %0, %1, off sc0" : "=v"(v) : "v"(p));
  return v;
}

// Genuine atomic RMW at the issuing XCD's L2 (r5-proven). ~300cy round trip.
__device__ __forceinline__ unsigned l2_rmw_add(unsigned* p, unsigned val) {
  unsigned v;
  asm volatile("global_atomic_add %0, %1, %2, off sc0\n\ts_waitcnt vmcnt(0)"
               : "=v"(v) : "v"(p), "v"(val) : "memory");
  return v;
}

// XCD-local barrier (r5/r7/r10-proven, best of 5 tested variants): all-RMW
// arrive+poll on one L2 line, s_sleep(2) backoff, buffer_inv exactly ONCE at
// exit (r6 lesson). pref=true: waves 4..7 entered with 8 prefetch loads in
// flight issued AFTER their stores; vmcnt(8) drains exactly the stores
// (release) while the loads fly through the barrier wait.
__device__ __forceinline__ void xbar(unsigned* cnt, bool pref) {
  if (pref && threadIdx.x >= 256)
    asm volatile("s_waitcnt vmcnt(8)" ::: "memory");
  else
    asm volatile("s_waitcnt vmcnt(0)" ::: "memory");
  __syncthreads();
  if (threadIdx.x == 0) {
    unsigned old = l2_rmw_add(cnt, 1u);
    unsigned target = (old & ~31u) + 32u;
    int guard = 1 << 16;
    while (l2_rmw_add(cnt, 0u) < target && --guard)
      __builtin_amdgcn_s_sleep(2);
  }
  __syncthreads();
  asm volatile("buffer_inv" ::: "memory");   // L1-only invalidate, once
  __builtin_amdgcn_sched_barrier(0);
}

// ---------------- fused prep kernel ----------------
__global__ void prep_all(const float* __restrict__ Wih, const float* __restrict__ Whh,
                         const float* __restrict__ bih, const float* __restrict__ bhh,
                         const float* __restrict__ Wvis, const float* __restrict__ feat,
                         const float* __restrict__ embed, const float* __restrict__ W1,
                         const float* __restrict__ W2,
                         _Float16* __restrict__ Wp, float* __restrict__ bp,
                         _Float16* __restrict__ Wvis16, _Float16* __restrict__ feat16,
                         _Float16* __restrict__ x0, _Float16* __restrict__ W1h,
                         _Float16* __restrict__ W2h, unsigned* __restrict__ cnt) {
  size_t idx = (size_t)blockIdx.x * 256 + threadIdx.x;   // 3*2048*1024 total
  {
    int k = (int)(idx & 1023);
    int R = (int)((idx >> 10) & 2047);
    int l = (int)(idx >> 21);
    int dt = R >> 6, g = (R >> 4) & 3, di = R & 15;
    int col = g * 512 + dt * 16 + di;
    float v = (k < 512) ? Wih[((size_t)l * NH4 + col) * ND + k]
                        : Whh[((size_t)l * NH4 + col) * ND + (k - 512)];
    Wp[idx] = (_Float16)v;
  }
  if (idx < (size_t)NL * NH4) {
    int R = (int)(idx & 2047);
    int l = (int)(idx >> 11);
    int dt = R >> 6, g = (R >> 4) & 3, di = R & 15;
    int col = g * 512 + dt * 16 + di;
    bp[idx] = bih[l * NH4 + col] + bhh[l * NH4 + col];
  }
  if (idx < 512 * 512)  Wvis16[idx] = (_Float16)Wvis[idx];
  if (idx < 256 * 512)  feat16[idx] = (_Float16)feat[idx];
  if (idx < 256 * 512)  x0[idx]     = (_Float16)embed[idx & 511];   // embed[START_IDX=0]
  if (idx < 1024 * 512) W1h[idx]    = (_Float16)W1[idx];
  if (idx < 128 * 1024) W2h[idx]    = (_Float16)W2[idx];
  if (idx < 1024) cnt[idx] = 0;
}

// ---------------- persistent LSTM kernel (r10 verbatim, proven 2105us) ----
__global__ __launch_bounds__(512, 2) void lstm_persist(
    const _Float16* __restrict__ Wp,     // [3][2048][1024] permuted
    const float* __restrict__ bp,        // [3][2048]
    const _Float16* __restrict__ Wvis,   // [512][512]
    const float* __restrict__ bvis,      // [512]
    const _Float16* __restrict__ feat16, // [256][512]
    const _Float16* __restrict__ x0,     // [256][512]
    _Float16* __restrict__ featp,        // [256][512]
    _Float16* __restrict__ hbuf,         // [3][2][256][512]
    _Float16* __restrict__ res,          // [201][256][512]
    unsigned* __restrict__ cntbase) {
  __shared__ _Float16 wlds[64][1024];          // 128KB layer-0 weights
  __shared__ float expart[4][32][16][4];       // 32KB: [slice][batch][di][gate]
  // total LDS = 163840 B exactly (gfx950 per-WG limit)

  const int tid = threadIdx.x;
  const int lane = tid & 63, w = tid >> 6;     // w = 0..7
  const int lr = lane & 15, lg = (lane >> 4) & 3;

  unsigned xcd;
  asm volatile("s_getreg_b32 %0, hwreg(HW_REG_XCC_ID)" : "=s"(xcd));
  xcd &= 7u;

  unsigned* rank_slot = (unsigned*)&expart[0][0][0][0];
  if (tid == 0)
    *rank_slot = __hip_atomic_fetch_add(cntbase + 256 + xcd * 32, 1u,
                                        __ATOMIC_RELAXED, __HIP_MEMORY_SCOPE_AGENT);
  __syncthreads();
  const int rank = (int)(*rank_slot & 31u);
  __syncthreads();

  const int dt = rank;                 // gate-row tile [dt*64, dt*64+64)
  const int m0 = (int)xcd * 32;        // batch slice
  const int d0 = rank * 16;            // hidden-dim slice
  unsigned* cnt = cntbase + xcd * 32;  // per-XCD barrier counter

  // ---- preload weights ----
  #pragma unroll 4
  for (int i = 0; i < 16; ++i) {               // layer 0 -> LDS
    int G = tid + 512 * i;
    int r = G >> 7, g = G & 127;
    *(half8*)&wlds[r][(g ^ (r & 7)) * 8] =
        *(const half8*)(Wp + ((size_t)(dt * 64 + r)) * 1024 + g * 8);
  }
  half8 wreg[2][4][4];                         // layers 1,2: K=128 slice per wave
  #pragma unroll
  for (int ly = 0; ly < 2; ++ly)
    #pragma unroll
    for (int n = 0; n < 4; ++n)
      #pragma unroll
      for (int kk = 0; kk < 4; ++kk)
        wreg[ly][n][kk] = *(const half8*)(Wp +
          ((size_t)((ly + 1) * NH4 + dt * 64 + n * 16 + lr)) * 1024 + w * 128 + kk * 32 + lg * 8);

  const int di = tid & 15, cb = (tid >> 4) & 31;
  f32x4 breg4[3];                              // bias as gate-vector
  #pragma unroll
  for (int l = 0; l < 3; ++l)
    #pragma unroll
    for (int g = 0; g < 4; ++g)
      breg4[l][g] = bp[l * NH4 + dt * 64 + g * 16 + di];

  // ---- prologue: feat_p = feat@Wvis^T+bvis ; h0 = feat_p@Wvis^T+bvis ----
  {
    float* xb = &expart[0][0][0][0];
    const int wm2 = w & 1, wk = w >> 1;
    #pragma unroll 1
    for (int pg = 0; pg < 2; ++pg) {
      const _Float16* A = pg ? featp : feat16;
      half8 avp[4];
      #pragma unroll
      for (int kc = 0; kc < 4; ++kc)
        avp[kc] = l2_load(A + (size_t)(m0 + wm2 * 16 + lr) * ND + wk * 128 + kc * 32 + lg * 8);
      asm volatile("s_waitcnt vmcnt(0)" ::: "memory");
      __builtin_amdgcn_sched_barrier(0);
      f32x4 pacc = {0.f, 0.f, 0.f, 0.f};
      #pragma unroll
      for (int kc = 0; kc < 4; ++kc) {
        half8 bb = *(const half8*)(Wvis + (size_t)(d0 + lr) * ND + wk * 128 + kc * 32 + lg * 8);
        pacc = __builtin_amdgcn_mfma_f32_16x16x32_f16(avp[kc], bb, pacc, 0, 0, 0);
      }
      #pragma unroll
      for (int j = 0; j < 4; ++j)
        xb[wk * 512 + (wm2 * 16 + lg * 4 + j) * 16 + lr] = pacc[j];
      __syncthreads();
      {
        int m = tid >> 4, d = tid & 15;
        float v = xb[m * 16 + d] + xb[512 + m * 16 + d] + xb[1024 + m * 16 + d]
                + xb[1536 + m * 16 + d] + bvis[d0 + d];
        _Float16 hv = (_Float16)v;
        size_t off = (size_t)(m0 + m) * ND + d0 + d;
        if (pg == 0) featp[off] = hv;
        else {
          hbuf[(size_t)(0 * 2 + 1) * (NB * ND) + off] = hv;
          hbuf[(size_t)(1 * 2 + 1) * (NB * ND) + off] = hv;
          hbuf[(size_t)(2 * 2 + 1) * (NB * ND) + off] = hv;
        }
      }
      xbar(cnt, false);
    }
  }

  // ---- main recurrence: 603 units ----
  float cst[3] = {0.f, 0.f, 0.f};
  const size_t aoff0 = (size_t)(m0 + lr) * ND + (size_t)(w & 3) * 128 + lg * 8;
  const size_t aoff1 = aoff0 + (size_t)16 * ND;
  half8 av0[4], av1[4];

  #pragma unroll 1
  for (int t = 0; t < NT; ++t) {
    #pragma unroll
    for (int l = 0; l < 3; ++l) {
      const _Float16* xsrc = (l == 0)
        ? ((t == 0) ? x0 : hbuf + (size_t)(2 * 2 + ((t + 1) & 1)) * (NB * ND))
        : hbuf + (size_t)((l - 1) * 2 + (t & 1)) * (NB * ND);
      const _Float16* hsrc = hbuf + (size_t)(l * 2 + ((t + 1) & 1)) * (NB * ND);
      _Float16* hdst       = hbuf + (size_t)(l * 2 + (t & 1)) * (NB * ND);

      f32x4 acc[2][4];
      #pragma unroll
      for (int m = 0; m < 2; ++m)
        #pragma unroll
        for (int n = 0; n < 4; ++n)
          acc[m][n] = (f32x4){0.f, 0.f, 0.f, 0.f};

      if (w < 4) {
        // x-half: fresh, load post-barrier; staged tie-dep drains (r9).
        #pragma unroll
        for (int kk = 0; kk < 4; ++kk) {
          av0[kk] = l2_load(xsrc + aoff0 + kk * 32);
          av1[kk] = l2_load(xsrc + aoff1 + kk * 32);
        }
        asm volatile("s_waitcnt vmcnt(4)"
                     : "+v"(av0[0]), "+v"(av0[1]), "+v"(av1[0]), "+v"(av1[1]));
        __builtin_amdgcn_s_setprio(1);
        #pragma unroll
        for (int kk = 0; kk < 2; ++kk)
          #pragma unroll
          for (int n = 0; n < 4; ++n) {
            half8 bf;
            if (l == 0) {
              int kg = w * 16 + kk * 4 + lg;
              bf = *(const half8*)&wlds[n * 16 + lr][(kg ^ (lr & 7)) * 8];
            } else bf = wreg[l - 1][n][kk];
            acc[0][n] = __builtin_amdgcn_mfma_f32_16x16x32_f16(av0[kk], bf, acc[0][n], 0, 0, 0);
            acc[1][n] = __builtin_amdgcn_mfma_f32_16x16x32_f16(av1[kk], bf, acc[1][n], 0, 0, 0);
          }
        __builtin_amdgcn_s_setprio(0);
        asm volatile("s_waitcnt vmcnt(0)"
                     : "+v"(av0[2]), "+v"(av0[3]), "+v"(av1[2]), "+v"(av1[3]));
        __builtin_amdgcn_s_setprio(1);
        #pragma unroll
        for (int kk = 2; kk < 4; ++kk)
          #pragma unroll
          for (int n = 0; n < 4; ++n) {
            half8 bf;
            if (l == 0) {
              int kg = w * 16 + kk * 4 + lg;
              bf = *(const half8*)&wlds[n * 16 + lr][(kg ^ (lr & 7)) * 8];
            } else bf = wreg[l - 1][n][kk];
            acc[0][n] = __builtin_amdgcn_mfma_f32_16x16x32_f16(av0[kk], bf, acc[0][n], 0, 0, 0);
            acc[1][n] = __builtin_amdgcn_mfma_f32_16x16x32_f16(av1[kk], bf, acc[1][n], 0, 0, 0);
          }
        __builtin_amdgcn_s_setprio(0);
      } else {
        if (t == 0 && l == 0) {        // first unit: h0 not prefetched
          #pragma unroll
          for (int kk = 0; kk < 4; ++kk) {
            av0[kk] = l2_load(hsrc + aoff0 + kk * 32);
            av1[kk] = l2_load(hsrc + aoff1 + kk * 32);
          }
        }
        asm volatile("s_waitcnt vmcnt(0)"
                     : "+v"(av0[0]), "+v"(av0[1]), "+v"(av0[2]), "+v"(av0[3]),
                       "+v"(av1[0]), "+v"(av1[1]), "+v"(av1[2]), "+v"(av1[3]));
        __builtin_amdgcn_s_setprio(1);
        #pragma unroll
        for (int kk = 0; kk < 4; ++kk)
          #pragma unroll
          for (int n = 0; n < 4; ++n) {
            half8 bf;
            if (l == 0) {
              int kg = w * 16 + kk * 4 + lg;
              bf = *(const half8*)&wlds[n * 16 + lr][(kg ^ (lr & 7)) * 8];
            } else bf = wreg[l - 1][n][kk];
            acc[0][n] = __builtin_amdgcn_mfma_f32_16x16x32_f16(av0[kk], bf, acc[0][n], 0, 0, 0);
            acc[1][n] = __builtin_amdgcn_mfma_f32_16x16x32_f16(av1[kk], bf, acc[1][n], 0, 0, 0);
          }
        __builtin_amdgcn_s_setprio(0);
      }

      // ---- exchange, gate-transposed: [slice][batch][di][gate] ----
      if (w >= 4) {
        #pragma unroll
        for (int m = 0; m < 2; ++m)
          #pragma unroll
          for (int j = 0; j < 4; ++j) {
            f32x4 v = {acc[m][0][j], acc[m][1][j], acc[m][2][j], acc[m][3][j]};
            *(f32x4*)&expart[w - 4][m * 16 + lg * 4 + j][lr][0] = v;
          }
      }
      __syncthreads();
      if (w < 4) {
        #pragma unroll
        for (int m = 0; m < 2; ++m)
          #pragma unroll
          for (int j = 0; j < 4; ++j) {
            f32x4* pp = (f32x4*)&expart[w][m * 16 + lg * 4 + j][lr][0];
            f32x4 tv = *pp;
            tv[0] += acc[m][0][j]; tv[1] += acc[m][1][j];
            tv[2] += acc[m][2][j]; tv[3] += acc[m][3][j];
            *pp = tv;
          }
      }
      __syncthreads();

      // ---- cell update: one cell per thread; gather = 4x ds_read_b128 ----
      {
        f32x4 s4 = breg4[l];
        #pragma unroll
        for (int s = 0; s < 4; ++s) {
          f32x4 g = *(const f32x4*)&expart[s][cb][di][0];
          s4 += g;
        }
        float c = cst[l];
        c = sigf(s4[1]) * c + sigf(s4[0]) * tanh_(s4[2]);
        cst[l] = c;
        _Float16 hv = (_Float16)(sigf(s4[3]) * tanh_(c));
        size_t off = (size_t)(m0 + cb) * ND + d0 + di;
        hdst[off] = hv;
        if (l == 2) res[(size_t)t * (NB * ND) + off] = hv;
      }

      if (!(t == NT - 1 && l == 2)) {
        if (w >= 4) {                    // prefetch next unit's h-half (2 barriers old)
          const int nt2 = (l == 2) ? t + 1 : t;
          const int nl  = (l == 2) ? 0 : l + 1;
          const _Float16* nh = hbuf + (size_t)(nl * 2 + ((nt2 + 1) & 1)) * (NB * ND);
          #pragma unroll
          for (int kk = 0; kk < 4; ++kk) {
            av0[kk] = l2_load(nh + aoff0 + kk * 32);
            av1[kk] = l2_load(nh + aoff1 + kk * 32);
          }
        }
        xbar(cnt, true);
      }
      // last unit: stream order publishes res to the head kernel
    }
  }
}

// ---------------- fused MLP head v2 ----------------
// r13: waves split over mid-COLUMNS, not rows. Wave w computes mid chunk
// c = rr*4+w (128 cols, all 64 rows) into its own LDS buffer -> W1h read
// exactly once per tile (was 4x duplicated). GEMM2 splits the 128 vocab
// cols 4 ways (32/wave, K accumulated across both rounds' chunk buffers).
// B-traffic per tile: 1MB W1h + 0.25MB W2h, no duplication (~2.9x less L2).
__global__ __launch_bounds__(256, 2) void head_kernel(
    const _Float16* __restrict__ res,  // [51456][512]
    const _Float16* __restrict__ W1h,  // [1024][512]
    const float* __restrict__ b1,      // [1024]
    const _Float16* __restrict__ W2h,  // [128][1024]
    const float* __restrict__ b2,      // [128]
    float* __restrict__ out) {         // [256][128][201]
  const int tid = threadIdx.x;
  const int lane = tid & 63, w = tid >> 6;     // 4 waves
  const int lr = lane & 15, lg = (lane >> 4) & 3;
  const int r0 = blockIdx.x * 64;

  __shared__ _Float16 mid[4][64][128];         // 64KB: one chunk buffer per wave

  f32x4 acc2[4][2];                            // [m-frag][v-frag] for 32 v-cols
  #pragma unroll
  for (int m = 0; m < 4; ++m)
    #pragma unroll
    for (int n2 = 0; n2 < 2; ++n2) acc2[m][n2] = (f32x4){0.f, 0.f, 0.f, 0.f};

  #pragma unroll 1
  for (int rr = 0; rr < 2; ++rr) {
    const int c = rr * 4 + w;                  // this wave's mid chunk (of 8)
    #pragma unroll 1
    for (int nh = 0; nh < 2; ++nh) {           // two 64-col halves (VGPR cap)
      f32x4 acc1[4][4];
      #pragma unroll
      for (int m = 0; m < 4; ++m)
        #pragma unroll
        for (int n = 0; n < 4; ++n) acc1[m][n] = (f32x4){0.f, 0.f, 0.f, 0.f};
      #pragma unroll 2
      for (int kc = 0; kc < 16; ++kc) {
        half8 af[4];
        #pragma unroll
        for (int m = 0; m < 4; ++m)
          af[m] = *(const half8*)(res + (size_t)(r0 + m * 16 + lr) * ND + kc * 32 + lg * 8);
        #pragma unroll
        for (int n = 0; n < 4; ++n) {
          half8 bb = *(const half8*)(W1h +
              (size_t)(c * 128 + nh * 64 + n * 16 + lr) * ND + kc * 32 + lg * 8);
          #pragma unroll
          for (int m = 0; m < 4; ++m)
            acc1[m][n] = __builtin_amdgcn_mfma_f32_16x16x32_f16(af[m], bb, acc1[m][n], 0, 0, 0);
        }
      }
      // gelu + store this half into the wave's chunk buffer (XOR-swizzled)
      #pragma unroll
      for (int n = 0; n < 4; ++n)
        #pragma unroll
        for (int m = 0; m < 4; ++m)
          #pragma unroll
          for (int j = 0; j < 4; ++j) {
            int row = m * 16 + lg * 4 + j;
            int col = nh * 64 + n * 16 + lr;
            float v = acc1[m][n][j] + b1[c * 128 + col];
            v = 0.5f * v * (1.0f + erff(v * 0.7071067811865475f));   // exact gelu
            int sw = (((col >> 3) ^ (row & 15)) << 3) + (col & 7);
            mid[w][row][sw] = (_Float16)v;
          }
    }
    __syncthreads();                           // all 4 chunk buffers ready
    // GEMM2 partial: this round's 512 K-slice (4 chunks x 128)
    #pragma unroll 1
    for (int s = 0; s < 4; ++s) {
      #pragma unroll
      for (int kc2 = 0; kc2 < 4; ++kc2) {
        half8 a2[4];
        #pragma unroll
        for (int m = 0; m < 4; ++m) {
          int row = m * 16 + lr;
          int blk = (kc2 * 4 + lg) ^ (row & 15);
          a2[m] = *(const half8*)&mid[s][row][blk * 8];
        }
        #pragma unroll
        for (int n2 = 0; n2 < 2; ++n2) {
          half8 bb = *(const half8*)(W2h +
              (size_t)(w * 32 + n2 * 16 + lr) * NMID + rr * 512 + s * 128 + kc2 * 32 + lg * 8);
          #pragma unroll
          for (int m = 0; m < 4; ++m)
            acc2[m][n2] = __builtin_amdgcn_mfma_f32_16x16x32_f16(a2[m], bb, acc2[m][n2], 0, 0, 0);
        }
      }
    }
    __syncthreads();                           // guard mid overwrite next round
  }
  // store: wave w owns vocab cols [w*32, w*32+32)
  #pragma unroll
  for (int n2 = 0; n2 < 2; ++n2)
    #pragma unroll
    for (int m = 0; m < 4; ++m)
      #pragma unroll
      for (int j = 0; j < 4; ++j) {
        int r = r0 + m * 16 + lg * 4 + j;
        int b = r & 255, t = r >> 8;           // rows are r = t*256 + b
        int v = w * 32 + n2 * 16 + lr;
        out[((size_t)b * NV + v) * NT + t] = acc2[m][n2][j] + b2[v];
      }
}

// ---------------- launch ----------------
extern "C" void kernel_launch(void* const* d_in, const int* in_sizes, int n_in,
                              void* d_out, int out_size, void* d_ws, size_t ws_size,
                              hipStream_t stream) {
  const float* feat  = (const float*)d_in[0];
  const float* Wvis  = (const float*)d_in[1];
  const float* bvis  = (const float*)d_in[2];
  const float* embed = (const float*)d_in[3];
  const float* Wih   = (const float*)d_in[4];
  const float* Whh   = (const float*)d_in[5];
  const float* bih   = (const float*)d_in[6];
  const float* bhh   = (const float*)d_in[7];
  const float* W1    = (const float*)d_in[8];
  const float* b1    = (const float*)d_in[9];
  const float* W2    = (const float*)d_in[10];
  const float* b2    = (const float*)d_in[11];
  float* out = (float*)d_out;

  char* p = (char*)d_ws;
  _Float16* Wp     = (_Float16*)p; p += (size_t)NL * NH4 * 1024 * 2;   // 12.58 MB
  _Float16* Wvis16 = (_Float16*)p; p += (size_t)512 * 512 * 2;
  _Float16* feat16 = (_Float16*)p; p += (size_t)256 * 512 * 2;
  _Float16* x0     = (_Float16*)p; p += (size_t)256 * 512 * 2;
  _Float16* featp  = (_Float16*)p; p += (size_t)256 * 512 * 2;
  _Float16* hbuf   = (_Float16*)p; p += (size_t)NL * 2 * NB * ND * 2;
  _Float16* resb   = (_Float16*)p; p += (size_t)NT * NB * ND * 2;      // 52.7 MB
  _Float16* W1h    = (_Float16*)p; p += (size_t)NMID * ND * 2;
  _Float16* W2h    = (_Float16*)p; p += (size_t)NV * NMID * 2;
  float*    bp     = (float*)p;    p += (size_t)NL * NH4 * 4;
  unsigned* cnt    = (unsigned*)p; p += 4096;   // [0..255] barriers, [256..511] ranks

  prep_all<<<24576, 256, 0, stream>>>(Wih, Whh, bih, bhh, Wvis, feat, embed, W1, W2,
                                      Wp, bp, Wvis16, feat16, x0, W1h, W2h, cnt);
  lstm_persist<<<256, 512, 0, stream>>>(Wp, bp, Wvis16, bvis, feat16, x0,
                                        featp, hbuf, resb, cnt);
  head_kernel<<<804, 256, 0, stream>>>(resb, W1h, b1, W2h, b2, out);
  (void)in_sizes; (void)n_in; (void)out_size; (void)ws_size;
}